// Round 6
// baseline (776.721 us; speedup 1.0000x reference)
//
#include <hip/hip_runtime.h>
#include <hip/hip_bf16.h>
#include <stdint.h>

typedef __attribute__((ext_vector_type(8))) short short8;
typedef __attribute__((ext_vector_type(4))) float f32x4;

__device__ __forceinline__ unsigned short f2bf(float f) {
    union { float f; uint32_t u; } v; v.f = f;
    return (unsigned short)((v.u + 0x7FFFu + ((v.u >> 16) & 1u)) >> 16);
}

// Build W[j][k] (bf16, row-major 192x192): W[h*16+oc][g*16+ic] = kernel[cayley[inv[g],h]][oc][ic]
__global__ void build_w_kernel(const float* __restrict__ kern,
                               const int* __restrict__ cayley,
                               const int* __restrict__ inv,
                               unsigned short* __restrict__ Wbf) {
    int i = blockIdx.x * blockDim.x + threadIdx.x;
    if (i >= 192 * 192) return;
    int j = i / 192;
    int k = i - j * 192;
    int h = j >> 4, oc = j & 15;
    int g = k >> 4, ic = k & 15;
    int cidx = cayley[inv[g] * 12 + h];
    Wbf[i] = f2bf(kern[cidx * 256 + oc * 16 + ic]);
}

// out[n][j] = sum_k x[n][k] * W[j][k] + bias[j & 15]
// Persistent 256-thread blocks; W streams from L2 (73.7 KB resident). Each wave
// owns spw contiguous 16-row strips, register-prefetching next strip's x.
// MFMA operands SWAPPED: mfma(w, x) -> lane holds out[strip*16+l15][ct*16+lhi*4+r]
// -> one nontemporal dwordx4 store per (ct,lane).
// __launch_bounds__(256,4): cap VGPR at 128 (R4's uncapped 224 -> only 2 waves/SIMD,
// Occupancy 11%). Ledger: (512,4)->64, (512,2)->128, (1024,4)->64, bare->224.
// Live-reg analysis ~119 <= 128, so no spill expected.
__global__ __launch_bounds__(256, 4) void gemm_kernel(
    const float* __restrict__ x,
    const unsigned short* __restrict__ Wbf,
    const float* __restrict__ bias,
    float* __restrict__ out, int nstrips, int spw) {
  const int tid  = threadIdx.x;
  const int lane = tid & 63;
  const int wid  = tid >> 6;
  const int l15  = lane & 15;
  const int lhi  = lane >> 4;

  const int gw = blockIdx.x * 4 + wid;    // global wave id
  int strip = gw * spw;
  const int send = min(strip + spw, nstrips);
  if (strip >= send) return;

  // bias for this lane's 4 output features (j = ct*16 + lhi*4 + r -> oc = lhi*4+r)
  const f32x4 bias4 = *(const f32x4*)(bias + lhi * 4);

  f32x4 araw[12];
  {
    const float* xr = x + (size_t)(strip * 16 + l15) * 192 + lhi * 8;
    #pragma unroll
    for (int c = 0; c < 6; ++c) {
      araw[2 * c]     = *(const f32x4*)(xr + c * 32);
      araw[2 * c + 1] = *(const f32x4*)(xr + c * 32 + 4);
    }
  }

  while (strip < send) {
    // Convert current strip's x to bf16 fragments (waits on the 12 loads).
    short8 abf[6];
    #pragma unroll
    for (int c = 0; c < 6; ++c) {
      short8 v;
      #pragma unroll
      for (int e = 0; e < 4; ++e) {
        v[e]     = (short)f2bf(araw[2 * c][e]);
        v[e + 4] = (short)f2bf(araw[2 * c + 1][e]);
      }
      abf[c] = v;
    }

    // Prefetch next strip's x (after conversion frees araw).
    const int nxt = strip + 1;
    if (nxt < send) {
      const float* xr = x + (size_t)(nxt * 16 + l15) * 192 + lhi * 8;
      #pragma unroll
      for (int c = 0; c < 6; ++c) {
        araw[2 * c]     = *(const f32x4*)(xr + c * 32);
        araw[2 * c + 1] = *(const f32x4*)(xr + c * 32 + 4);
      }
    }

    // n-row for this lane's stores: strip*16 + l15
    float* obase = out + (size_t)(strip * 16 + l15) * 192 + lhi * 4;
    #pragma unroll
    for (int ct = 0; ct < 12; ++ct) {
      // W fragment: lane holds W[ct*16 + l15][c*32 + lhi*8 .. +7]
      const unsigned short* wr = Wbf + (size_t)(ct * 16 + l15) * 192 + lhi * 8;
      f32x4 acc = {0.f, 0.f, 0.f, 0.f};
      #pragma unroll
      for (int c = 0; c < 6; ++c) {
        short8 w = *(const short8*)(wr + c * 32);
        acc = __builtin_amdgcn_mfma_f32_16x16x32_bf16(w, abf[c], acc, 0, 0, 0);
      }
      f32x4 res = {acc[0] + bias4[0], acc[1] + bias4[1],
                   acc[2] + bias4[2], acc[3] + bias4[3]};
      __builtin_nontemporal_store(res, (f32x4*)(obase + ct * 16));
    }
    strip = nxt;
  }
}

extern "C" void kernel_launch(void* const* d_in, const int* in_sizes, int n_in,
                              void* d_out, int out_size, void* d_ws, size_t ws_size,
                              hipStream_t stream) {
    const float* x      = (const float*)d_in[0];
    const float* kern   = (const float*)d_in[1];
    const float* bias   = (const float*)d_in[2];
    const int*   cayley = (const int*)d_in[3];
    const int*   inv    = (const int*)d_in[4];
    float* out = (float*)d_out;
    unsigned short* Wbf = (unsigned short*)d_ws;   // 192*192*2 = 73728 bytes

    const int nrows = in_sizes[0] / 192;
    const int nstrips = nrows / 16;                // 32768

    build_w_kernel<<<(192 * 192 + 255) / 256, 256, 0, stream>>>(kern, cayley, inv, Wbf);

    const int nblocks = 1024;                      // persistent
    const int nwaves  = nblocks * 4;
    const int spw     = (nstrips + nwaves - 1) / nwaves;   // = 8
    gemm_kernel<<<nblocks, 256, 0, stream>>>(x, Wbf, bias, out, nstrips, spw);
}

// Round 7
// 392.417 us; speedup vs baseline: 1.9793x; 1.9793x over previous
//
#include <hip/hip_runtime.h>
#include <hip/hip_bf16.h>
#include <stdint.h>

typedef __attribute__((ext_vector_type(8))) short short8;
typedef __attribute__((ext_vector_type(4))) float f32x4;

__device__ __forceinline__ unsigned short f2bf(float f) {
    union { float f; uint32_t u; } v; v.f = f;
    return (unsigned short)((v.u + 0x7FFFu + ((v.u >> 16) & 1u)) >> 16);
}

// Build W[j][k] (bf16, row-major 192x192): W[h*16+oc][g*16+ic] = kernel[cayley[inv[g],h]][oc][ic]
__global__ void build_w_kernel(const float* __restrict__ kern,
                               const int* __restrict__ cayley,
                               const int* __restrict__ inv,
                               unsigned short* __restrict__ Wbf) {
    int i = blockIdx.x * blockDim.x + threadIdx.x;
    if (i >= 192 * 192) return;
    int j = i / 192;
    int k = i - j * 192;
    int h = j >> 4, oc = j & 15;
    int g = k >> 4, ic = k & 15;
    int cidx = cayley[inv[g] * 12 + h];
    Wbf[i] = f2bf(kern[cidx * 256 + oc * 16 + ic]);
}

// out[n][j] = sum_k x[n][k] * W[j][k] + bias[j & 15]
// Persistent 256-thread blocks; W streams from L2 (73.7 KB resident). Each wave
// owns spw contiguous 16-row strips, register-prefetching next strip's x.
// MFMA operands SWAPPED: mfma(w, x) -> lane holds out[strip*16+l15][ct*16+lhi*4+r]
// -> one nontemporal dwordx4 store per (ct,lane).
// VGPR-cap ledger (empirical: cap = 256/arg2, any block size):
//   (512,4)->64 spill, (512,2)->128 ok, (1024,4)->64 spill, (256,4)->64 spill,
//   bare->224 (occupancy 11%). (256,2) => 128 cap; live regs ~119 -> no spill;
//   HW still runs 4 waves/SIMD at 128 VGPR (R2 measured 46.7% occ @128).
__global__ __launch_bounds__(256, 2) void gemm_kernel(
    const float* __restrict__ x,
    const unsigned short* __restrict__ Wbf,
    const float* __restrict__ bias,
    float* __restrict__ out, int nstrips, int spw) {
  const int tid  = threadIdx.x;
  const int lane = tid & 63;
  const int wid  = tid >> 6;
  const int l15  = lane & 15;
  const int lhi  = lane >> 4;

  const int gw = blockIdx.x * 4 + wid;    // global wave id
  int strip = gw * spw;
  const int send = min(strip + spw, nstrips);
  if (strip >= send) return;

  // bias for this lane's 4 output features (j = ct*16 + lhi*4 + r -> oc = lhi*4+r)
  const f32x4 bias4 = *(const f32x4*)(bias + lhi * 4);

  f32x4 araw[12];
  {
    const float* xr = x + (size_t)(strip * 16 + l15) * 192 + lhi * 8;
    #pragma unroll
    for (int c = 0; c < 6; ++c) {
      araw[2 * c]     = *(const f32x4*)(xr + c * 32);
      araw[2 * c + 1] = *(const f32x4*)(xr + c * 32 + 4);
    }
  }

  while (strip < send) {
    // Convert current strip's x to bf16 fragments (waits on the 12 loads).
    short8 abf[6];
    #pragma unroll
    for (int c = 0; c < 6; ++c) {
      short8 v;
      #pragma unroll
      for (int e = 0; e < 4; ++e) {
        v[e]     = (short)f2bf(araw[2 * c][e]);
        v[e + 4] = (short)f2bf(araw[2 * c + 1][e]);
      }
      abf[c] = v;
    }

    // Prefetch next strip's x (after conversion frees araw).
    const int nxt = strip + 1;
    if (nxt < send) {
      const float* xr = x + (size_t)(nxt * 16 + l15) * 192 + lhi * 8;
      #pragma unroll
      for (int c = 0; c < 6; ++c) {
        araw[2 * c]     = *(const f32x4*)(xr + c * 32);
        araw[2 * c + 1] = *(const f32x4*)(xr + c * 32 + 4);
      }
    }

    // n-row for this lane's stores: strip*16 + l15
    float* obase = out + (size_t)(strip * 16 + l15) * 192 + lhi * 4;
    #pragma unroll
    for (int ct = 0; ct < 12; ++ct) {
      // W fragment: lane holds W[ct*16 + l15][c*32 + lhi*8 .. +7]
      const unsigned short* wr = Wbf + (size_t)(ct * 16 + l15) * 192 + lhi * 8;
      f32x4 acc = {0.f, 0.f, 0.f, 0.f};
      #pragma unroll
      for (int c = 0; c < 6; ++c) {
        short8 w = *(const short8*)(wr + c * 32);
        acc = __builtin_amdgcn_mfma_f32_16x16x32_bf16(w, abf[c], acc, 0, 0, 0);
      }
      f32x4 res = {acc[0] + bias4[0], acc[1] + bias4[1],
                   acc[2] + bias4[2], acc[3] + bias4[3]};
      __builtin_nontemporal_store(res, (f32x4*)(obase + ct * 16));
    }
    strip = nxt;
  }
}

extern "C" void kernel_launch(void* const* d_in, const int* in_sizes, int n_in,
                              void* d_out, int out_size, void* d_ws, size_t ws_size,
                              hipStream_t stream) {
    const float* x      = (const float*)d_in[0];
    const float* kern   = (const float*)d_in[1];
    const float* bias   = (const float*)d_in[2];
    const int*   cayley = (const int*)d_in[3];
    const int*   inv    = (const int*)d_in[4];
    float* out = (float*)d_out;
    unsigned short* Wbf = (unsigned short*)d_ws;   // 192*192*2 = 73728 bytes

    const int nrows = in_sizes[0] / 192;
    const int nstrips = nrows / 16;                // 32768

    build_w_kernel<<<(192 * 192 + 255) / 256, 256, 0, stream>>>(kern, cayley, inv, Wbf);

    const int nblocks = 1024;                      // persistent
    const int nwaves  = nblocks * 4;
    const int spw     = (nstrips + nwaves - 1) / nwaves;   // = 8
    gemm_kernel<<<nblocks, 256, 0, stream>>>(x, Wbf, bias, out, nstrips, spw);
}

// Round 8
// 324.731 us; speedup vs baseline: 2.3919x; 1.2084x over previous
//
#include <hip/hip_runtime.h>
#include <hip/hip_bf16.h>
#include <stdint.h>

typedef __attribute__((ext_vector_type(8))) short short8;
typedef __attribute__((ext_vector_type(4))) float f32x4;

__device__ __forceinline__ unsigned short f2bf(float f) {
    union { float f; uint32_t u; } v; v.f = f;
    return (unsigned short)((v.u + 0x7FFFu + ((v.u >> 16) & 1u)) >> 16);
}

// Build W[j][k] (bf16, row-major 192x192): W[h*16+oc][g*16+ic] = kernel[cayley[inv[g],h]][oc][ic]
__global__ void build_w_kernel(const float* __restrict__ kern,
                               const int* __restrict__ cayley,
                               const int* __restrict__ inv,
                               unsigned short* __restrict__ Wbf) {
    int i = blockIdx.x * blockDim.x + threadIdx.x;
    if (i >= 192 * 192) return;
    int j = i / 192;
    int k = i - j * 192;
    int h = j >> 4, oc = j & 15;
    int g = k >> 4, ic = k & 15;
    int cidx = cayley[inv[g] * 12 + h];
    Wbf[i] = f2bf(kern[cidx * 256 + oc * 16 + ic]);
}

// out[n][j] = sum_k x[n][k] * W[j][k] + bias[j & 15]
// Persistent 256-thread blocks; W streams from L2 (73.7 KB resident).
// NO cross-strip register prefetch: R2/R6 proved it spills under the 128 cap
// (FETCH ~800 MB = x + 400 MB scratch); uncapped it costs 224 VGPR (11% occ, R4).
// Latency hiding via TLP instead: 128 VGPR -> 4 waves/SIMD = 16 waves/CU.
// MFMA operands SWAPPED: mfma(w, x) -> lane holds out[strip*16+l15][ct*16+lhi*4+r]
// -> one nontemporal dwordx4 store per (ct,lane).
// VGPR-cap ledger (empirical: cap = 256/arg2): (256,2) => 128.
__global__ __launch_bounds__(256, 2) void gemm_kernel(
    const float* __restrict__ x,
    const unsigned short* __restrict__ Wbf,
    const float* __restrict__ bias,
    float* __restrict__ out, int nstrips, int spw) {
  const int tid  = threadIdx.x;
  const int lane = tid & 63;
  const int wid  = tid >> 6;
  const int l15  = lane & 15;
  const int lhi  = lane >> 4;

  const int gw = blockIdx.x * 4 + wid;    // global wave id
  int strip = gw * spw;
  const int send = min(strip + spw, nstrips);
  if (strip >= send) return;

  // bias for this lane's 4 output features (j = ct*16 + lhi*4 + r -> oc = lhi*4+r)
  const f32x4 bias4 = *(const f32x4*)(bias + lhi * 4);

  while (strip < send) {
    // Load + convert this strip's x (staging f32 regs die right after cvt).
    short8 abf[6];
    {
      const float* xr = x + (size_t)(strip * 16 + l15) * 192 + lhi * 8;
      f32x4 f0[6], f1[6];
      #pragma unroll
      for (int c = 0; c < 6; ++c) {
        f0[c] = *(const f32x4*)(xr + c * 32);
        f1[c] = *(const f32x4*)(xr + c * 32 + 4);
      }
      #pragma unroll
      for (int c = 0; c < 6; ++c) {
        short8 v;
        #pragma unroll
        for (int e = 0; e < 4; ++e) {
          v[e]     = (short)f2bf(f0[c][e]);
          v[e + 4] = (short)f2bf(f1[c][e]);
        }
        abf[c] = v;
      }
    }

    // n-row for this lane's stores: strip*16 + l15
    float* obase = out + (size_t)(strip * 16 + l15) * 192 + lhi * 4;
    #pragma unroll
    for (int ct = 0; ct < 12; ++ct) {
      // W fragment: lane holds W[ct*16 + l15][c*32 + lhi*8 .. +7]
      const unsigned short* wr = Wbf + (size_t)(ct * 16 + l15) * 192 + lhi * 8;
      f32x4 acc = {0.f, 0.f, 0.f, 0.f};
      #pragma unroll
      for (int c = 0; c < 6; ++c) {
        short8 w = *(const short8*)(wr + c * 32);
        acc = __builtin_amdgcn_mfma_f32_16x16x32_bf16(w, abf[c], acc, 0, 0, 0);
      }
      f32x4 res = {acc[0] + bias4[0], acc[1] + bias4[1],
                   acc[2] + bias4[2], acc[3] + bias4[3]};
      __builtin_nontemporal_store(res, (f32x4*)(obase + ct * 16));
    }
    ++strip;
  }
}

extern "C" void kernel_launch(void* const* d_in, const int* in_sizes, int n_in,
                              void* d_out, int out_size, void* d_ws, size_t ws_size,
                              hipStream_t stream) {
    const float* x      = (const float*)d_in[0];
    const float* kern   = (const float*)d_in[1];
    const float* bias   = (const float*)d_in[2];
    const int*   cayley = (const int*)d_in[3];
    const int*   inv    = (const int*)d_in[4];
    float* out = (float*)d_out;
    unsigned short* Wbf = (unsigned short*)d_ws;   // 192*192*2 = 73728 bytes

    const int nrows = in_sizes[0] / 192;
    const int nstrips = nrows / 16;                // 32768

    build_w_kernel<<<(192 * 192 + 255) / 256, 256, 0, stream>>>(kern, cayley, inv, Wbf);

    const int nblocks = 1024;                      // persistent, 4 blocks/CU target
    const int nwaves  = nblocks * 4;
    const int spw     = (nstrips + nwaves - 1) / nwaves;   // = 8
    gemm_kernel<<<nblocks, 256, 0, stream>>>(x, Wbf, bias, out, nstrips, spw);
}

// Round 9
// 305.268 us; speedup vs baseline: 2.5444x; 1.0638x over previous
//
#include <hip/hip_runtime.h>
#include <hip/hip_bf16.h>
#include <stdint.h>

typedef __attribute__((ext_vector_type(8))) short short8;
typedef __attribute__((ext_vector_type(4))) float f32x4;
typedef __attribute__((ext_vector_type(4))) int int4v;

__device__ __forceinline__ unsigned short f2bf(float f) {
    union { float f; uint32_t u; } v; v.f = f;
    return (unsigned short)((v.u + 0x7FFFu + ((v.u >> 16) & 1u)) >> 16);
}

// Build W directly in MFMA-FRAGMENT order:
//   Wfrag[((ct*6 + c)*64 + lane)*8 + e] = bf16( W[ct*16 + (lane&15)][c*32 + (lane>>4)*8 + e] )
// where W[j][k] = kernel[cayley[inv[k>>4], j>>4]][j&15][k&15].
// Each wave's ds_read_b128 for (ct,c) is then lane-linear 16B -> conflict-free.
__global__ void build_w_kernel(const float* __restrict__ kern,
                               const int* __restrict__ cayley,
                               const int* __restrict__ inv,
                               unsigned short* __restrict__ Wfrag) {
    int i = blockIdx.x * blockDim.x + threadIdx.x;   // i = ((ct*6+c)*64 + lane)*8 + e
    if (i >= 192 * 192) return;
    int e    = i & 7;
    int lane = (i >> 3) & 63;
    int fc   = i >> 9;            // ct*6 + c
    int ct   = fc / 6, c = fc - ct * 6;
    int j = ct * 16 + (lane & 15);
    int k = c * 32 + (lane >> 4) * 8 + e;
    int h = j >> 4, oc = j & 15;
    int g = k >> 4, ic = k & 15;
    int cidx = cayley[inv[g] * 12 + h];
    Wfrag[i] = f2bf(kern[cidx * 256 + oc * 16 + ic]);
}

// out[n][j] = sum_k x[n][k] * W[j][k] + bias[j]
// Persistent 512-thread blocks (2/CU — empirically the max blocks/CU observed),
// (512,2) => 128-VGPR cap (ledger), spill-free single-buffer strip loop (R7),
// W in LDS in fragment order (73728 B; 2 blocks x 73.7 KB = 147 KB <= 160 KB, R2
// proved co-residency at 46.7% occupancy). No cross-strip register prefetch
// (spills under 128 cap, R2/R6). MFMA swapped: mfma(w, x) -> lane stores one
// nontemporal dwordx4 of out[strip*16+l15][ct*16+lhi*4 .. +3].
__global__ __launch_bounds__(512, 2) void gemm_kernel(
    const float* __restrict__ x,
    const unsigned short* __restrict__ Wfrag,
    const float* __restrict__ bias,
    float* __restrict__ out, int nstrips, int spw) {
  __shared__ unsigned char lds[192 * 192 * 2];   // 73728 B, fragment order
  const int tid  = threadIdx.x;
  const int lane = tid & 63;
  const int wid  = tid >> 6;
  const int l15  = lane & 15;
  const int lhi  = lane >> 4;

  // Stage W fragments into LDS (pure linear copy, 73728 B / 512 thr = 9 x int4).
  {
    const int4v* src = (const int4v*)Wfrag;
    int4v* dst = (int4v*)lds;
    #pragma unroll
    for (int t = 0; t < 9; ++t) dst[tid + t * 512] = src[tid + t * 512];
  }
  __syncthreads();

  const int gw = blockIdx.x * 8 + wid;    // global wave id
  int strip = gw * spw;
  const int send = min(strip + spw, nstrips);

  // bias for this lane's 4 output features (j = ct*16 + lhi*4 + r)
  const f32x4 bias4 = *(const f32x4*)(bias + lhi * 4);
  // LDS fragment base for this lane: frag (ct,c) at lane*16 + (ct*6+c)*1024
  const unsigned char* wbase = lds + lane * 16;

  while (strip < send) {
    // Load + convert this strip's x (staging f32 regs die right after cvt).
    short8 abf[6];
    {
      const float* xr = x + (size_t)(strip * 16 + l15) * 192 + lhi * 8;
      f32x4 f0[6], f1[6];
      #pragma unroll
      for (int c = 0; c < 6; ++c) {
        f0[c] = *(const f32x4*)(xr + c * 32);
        f1[c] = *(const f32x4*)(xr + c * 32 + 4);
      }
      #pragma unroll
      for (int c = 0; c < 6; ++c) {
        short8 v;
        #pragma unroll
        for (int e = 0; e < 4; ++e) {
          v[e]     = (short)f2bf(f0[c][e]);
          v[e + 4] = (short)f2bf(f1[c][e]);
        }
        abf[c] = v;
      }
    }

    float* obase = out + (size_t)(strip * 16 + l15) * 192 + lhi * 4;
    #pragma unroll
    for (int ct = 0; ct < 12; ++ct) {
      f32x4 acc = {0.f, 0.f, 0.f, 0.f};
      #pragma unroll
      for (int c = 0; c < 6; ++c) {
        short8 w = *(const short8*)(wbase + (ct * 6 + c) * 1024);
        acc = __builtin_amdgcn_mfma_f32_16x16x32_bf16(w, abf[c], acc, 0, 0, 0);
      }
      f32x4 res = {acc[0] + bias4[0], acc[1] + bias4[1],
                   acc[2] + bias4[2], acc[3] + bias4[3]};
      __builtin_nontemporal_store(res, (f32x4*)(obase + ct * 16));
    }
    ++strip;
  }
}

extern "C" void kernel_launch(void* const* d_in, const int* in_sizes, int n_in,
                              void* d_out, int out_size, void* d_ws, size_t ws_size,
                              hipStream_t stream) {
    const float* x      = (const float*)d_in[0];
    const float* kern   = (const float*)d_in[1];
    const float* bias   = (const float*)d_in[2];
    const int*   cayley = (const int*)d_in[3];
    const int*   inv    = (const int*)d_in[4];
    float* out = (float*)d_out;
    unsigned short* Wfrag = (unsigned short*)d_ws;   // 73728 bytes

    const int nrows = in_sizes[0] / 192;
    const int nstrips = nrows / 16;                  // 32768

    build_w_kernel<<<(192 * 192 + 255) / 256, 256, 0, stream>>>(kern, cayley, inv, Wfrag);

    const int nblocks = 512;                         // persistent, 2 blocks/CU
    const int nwaves  = nblocks * 8;                 // 4096 waves
    const int spw     = (nstrips + nwaves - 1) / nwaves;   // = 8
    gemm_kernel<<<nblocks, 512, 0, stream>>>(x, Wfrag, bias, out, nstrips, spw);
}

// Round 10
// 203.748 us; speedup vs baseline: 3.8122x; 1.4983x over previous
//
#include <hip/hip_runtime.h>
#include <hip/hip_bf16.h>
#include <stdint.h>

typedef __attribute__((ext_vector_type(8))) short short8;
typedef __attribute__((ext_vector_type(4))) float f32x4;
typedef __attribute__((ext_vector_type(4))) int int4v;

__device__ __forceinline__ unsigned short f2bf(float f) {
    union { float f; uint32_t u; } v; v.f = f;
    return (unsigned short)((v.u + 0x7FFFu + ((v.u >> 16) & 1u)) >> 16);
}

// Build W directly in MFMA-FRAGMENT order:
//   Wfrag[((ct*6 + c)*64 + lane)*8 + e] = bf16( W[ct*16 + (lane&15)][c*32 + (lane>>4)*8 + e] )
// where W[j][k] = kernel[cayley[inv[k>>4], j>>4]][j&15][k&15].
// Each wave's ds_read_b128 for (ct,c) is lane-linear 16B -> conflict-free (R8: 0 conflicts).
__global__ void build_w_kernel(const float* __restrict__ kern,
                               const int* __restrict__ cayley,
                               const int* __restrict__ inv,
                               unsigned short* __restrict__ Wfrag) {
    int i = blockIdx.x * blockDim.x + threadIdx.x;   // i = ((ct*6+c)*64 + lane)*8 + e
    if (i >= 192 * 192) return;
    int e    = i & 7;
    int lane = (i >> 3) & 63;
    int fc   = i >> 9;            // ct*6 + c
    int ct   = fc / 6, c = fc - ct * 6;
    int j = ct * 16 + (lane & 15);
    int k = c * 32 + (lane >> 4) * 8 + e;
    int h = j >> 4, oc = j & 15;
    int g = k >> 4, ic = k & 15;
    int cidx = cayley[inv[g] * 12 + h];
    Wfrag[i] = f2bf(kern[cidx * 256 + oc * 16 + ic]);
}

// out[n][j] = sum_k x[n][k] * W[j][k] + bias[j]
// Empirical occupancy law (R1/R2/R4/R7/R8): waves_per_SIMD ~= 256 / VGPR_Count
// (unified VGPR/AGPR file charges ~2x arch VGPRs). 128-VGPR configs are stuck at
// 2 waves/SIMD (22%); target 64 VGPR -> 4 waves/SIMD (~47%, R1-verified).
// To FIT 64 without the R1/R6 spills:
//   - staging in two sequential 6x dwordx4 batches (peak ~60 live regs)
//   - sched_barrier(0) at loop bottom: stops cross-strip load hoisting, the
//     source of R7/R8's ~190 MB/side scratch traffic under a register cap
//   - no cross-strip register prefetch; TLP (16 waves/CU) hides HBM latency
// W in LDS in fragment order (73728 B; 2 blocks/CU = 147 KB <= 160 KB).
// MFMA swapped: mfma(w, x) -> lane stores one NT dwordx4 of
// out[strip*16+l15][ct*16+lhi*4 .. +3].
__global__ __launch_bounds__(512, 4) void gemm_kernel(
    const float* __restrict__ x,
    const unsigned short* __restrict__ Wfrag,
    const float* __restrict__ bias,
    float* __restrict__ out, int nstrips, int spw) {
  __shared__ unsigned char lds[192 * 192 * 2];   // 73728 B, fragment order
  const int tid  = threadIdx.x;
  const int lane = tid & 63;
  const int wid  = tid >> 6;
  const int l15  = lane & 15;
  const int lhi  = lane >> 4;

  // Stage W fragments into LDS (pure linear copy, 73728 B / 512 thr = 9 x int4).
  {
    const int4v* src = (const int4v*)Wfrag;
    int4v* dst = (int4v*)lds;
    #pragma unroll
    for (int t = 0; t < 9; ++t) dst[tid + t * 512] = src[tid + t * 512];
  }
  __syncthreads();

  const int gw = blockIdx.x * 8 + wid;    // global wave id
  int strip = gw * spw;
  const int send = min(strip + spw, nstrips);

  // bias for this lane's 4 output features (j = ct*16 + lhi*4 + r)
  const f32x4 bias4 = *(const f32x4*)(bias + lhi * 4);
  // LDS fragment base for this lane: frag (ct,c) at lane*16 + (ct*6+c)*1024
  const unsigned char* wbase = lds + lane * 16;

  while (strip < send) {
    short8 abf[6];
    {
      const float* xr = x + (size_t)(strip * 16 + l15) * 192 + lhi * 8;
      // Batch A: lo halves (k = c*32 + lhi*8 + 0..3)
      f32x4 fa[6];
      #pragma unroll
      for (int c = 0; c < 6; ++c) fa[c] = *(const f32x4*)(xr + c * 32);
      #pragma unroll
      for (int c = 0; c < 6; ++c)
        #pragma unroll
        for (int e = 0; e < 4; ++e) abf[c][e] = (short)f2bf(fa[c][e]);
      // Batch B: hi halves (k = c*32 + lhi*8 + 4..7)
      f32x4 fb[6];
      #pragma unroll
      for (int c = 0; c < 6; ++c) fb[c] = *(const f32x4*)(xr + c * 32 + 4);
      #pragma unroll
      for (int c = 0; c < 6; ++c)
        #pragma unroll
        for (int e = 0; e < 4; ++e) abf[c][e + 4] = (short)f2bf(fb[c][e]);
    }

    float* obase = out + (size_t)(strip * 16 + l15) * 192 + lhi * 4;
    #pragma unroll
    for (int ct = 0; ct < 12; ++ct) {
      f32x4 acc = {0.f, 0.f, 0.f, 0.f};
      #pragma unroll
      for (int c = 0; c < 6; ++c) {
        short8 w = *(const short8*)(wbase + (ct * 6 + c) * 1024);
        acc = __builtin_amdgcn_mfma_f32_16x16x32_bf16(w, abf[c], acc, 0, 0, 0);
      }
      f32x4 res = {acc[0] + bias4[0], acc[1] + bias4[1],
                   acc[2] + bias4[2], acc[3] + bias4[3]};
      __builtin_nontemporal_store(res, (f32x4*)(obase + ct * 16));
    }
    ++strip;
    // Fence: forbid hoisting next strip's loads above this point (spill source).
    __builtin_amdgcn_sched_barrier(0);
  }
}

extern "C" void kernel_launch(void* const* d_in, const int* in_sizes, int n_in,
                              void* d_out, int out_size, void* d_ws, size_t ws_size,
                              hipStream_t stream) {
    const float* x      = (const float*)d_in[0];
    const float* kern   = (const float*)d_in[1];
    const float* bias   = (const float*)d_in[2];
    const int*   cayley = (const int*)d_in[3];
    const int*   inv    = (const int*)d_in[4];
    float* out = (float*)d_out;
    unsigned short* Wfrag = (unsigned short*)d_ws;   // 73728 bytes

    const int nrows = in_sizes[0] / 192;
    const int nstrips = nrows / 16;                  // 32768

    build_w_kernel<<<(192 * 192 + 255) / 256, 256, 0, stream>>>(kern, cayley, inv, Wfrag);

    const int nblocks = 512;                         // persistent, 2 blocks/CU
    const int nwaves  = nblocks * 8;                 // 4096 waves
    const int spw     = (nstrips + nwaves - 1) / nwaves;   // = 8
    gemm_kernel<<<nblocks, 512, 0, stream>>>(x, Wfrag, bias, out, nstrips, spw);
}